// Round 7
// baseline (34209.396 us; speedup 1.0000x reference)
//
#include <hip/hip_runtime.h>
#include <cstdint>
#include <cstddef>

#define HID   512
#define NB    64
#define SEQT  1000
#define NENT  550

#define NWG   256   // 128 wgs per layer
#define NTHR  256
#define SLICES 128  // wgs per layer; each owns 4 hidden units (16 gate cols)
#define KTOT  1024
#define KCH   128   // k-chunk (floats)
#define WP    1028  // Wl2 col pitch (floats): spreads banks (4*col mod 32)
#define GP    68    // glp row pitch (floats): 16B-aligned rows

typedef unsigned long long ull;
typedef float f32x4 __attribute__((ext_vector_type(4)));

__device__ __forceinline__ float sigm(float x) {
  x = fminf(fmaxf(x, -30.f), 30.f);
  return 1.f / (1.f + __expf(-x));
}
__device__ __forceinline__ float tanh_f(float x) {
  x = fminf(fmaxf(x, -15.f), 15.f);
  float e = __expf(2.f * x);
  return (e - 1.f) / (e + 1.f);
}
// write-through to LLC (never dirties per-XCD L2) — producer side of exchange
__device__ __forceinline__ void st_llc(float* p, float v) {
  __hip_atomic_store(p, v, __ATOMIC_RELAXED, __HIP_MEMORY_SCOPE_AGENT);
}
// L2-bypassing reads (served by LLC) — exchange buffers only (round-1-proven)
__device__ __forceinline__ ull ld_llc8(const float* p) {
  return __hip_atomic_load((const ull*)p, __ATOMIC_RELAXED, __HIP_MEMORY_SCOPE_AGENT);
}
__device__ __forceinline__ float ld_llc4(const float* p) {
  return __hip_atomic_load(p, __ATOMIC_RELAXED, __HIP_MEMORY_SCOPE_AGENT);
}

// One-time repack to [wg-slice][col][k], col = g*4 + u (u = unit in slice):
// Wp[((L*128+sl)*16 + col)*1024 + k] = W_L[k][g*512 + sl*4 + u]
__global__ void __launch_bounds__(256)
pack_w(const float* __restrict__ W0, const float* __restrict__ W1,
       float* __restrict__ Wp)
{
  const unsigned idx = blockIdx.x * 256u + threadIdx.x;  // over 2*128*16*1024
  const int k   = idx & (KTOT - 1);
  const int col = (idx >> 10) & 15;
  const int sl  = (idx >> 14) & (SLICES - 1);
  const int L   = idx >> 21;
  const float* W = L ? W1 : W0;
  Wp[idx] = W[(size_t)k * 2048 + (col >> 2) * HID + sl * 4 + (col & 3)];
}

__global__ void __launch_bounds__(NTHR, 1)
lstm_persistent(const int* __restrict__ tok, const int* __restrict__ len,
                const float* __restrict__ emb,
                const float* __restrict__ W0, const float* __restrict__ b0,
                const float* __restrict__ W1, const float* __restrict__ b1,
                const float* __restrict__ Wout, const float* __restrict__ bout,
                float* __restrict__ out, unsigned char* __restrict__ ws,
                const float* __restrict__ Wp, int packed)
{
  // LDS: 64.2 KB weights + 64 KB staging + 17 KB reduction = ~148.8 KB (<160)
  __shared__ float Wl2[16 * WP];          // [col][k], col = g*4 + u
  __shared__ float inl2[2][4][8][64][4];  // [buf][seg][jj][row][e] staging
  __shared__ float glp[NB * GP];          // K-partial exchange
  __shared__ float bl[16];
  __shared__ int   s_maxlen;

  const int tid = threadIdx.x;
  const int wg  = blockIdx.x;
  const int L   = wg >> 7;              // 0: layer0, 1: layer1
  const int sl  = wg & (SLICES - 1);    // slice (4 hidden units)

  unsigned* cnt = (unsigned*)ws;
  float* h0b   = (float*)(ws + 256);        // [2][NB][HID]
  float* h1b   = h0b + 2 * NB * HID;
  float* y0b   = h1b + 2 * NB * HID;
  float* lastb = y0b + 2 * NB * HID;        // [NB][HID]

  const float* Wsrc = L ? W1 : W0;
  const float* bsrc = L ? b1 : b0;

  const int b   = tid & 63;        // lane = staging row (batch)
  const int seg = tid >> 6;        // wave id = k-window owner + reduction seg
  const int bq  = tid & 15;        // lane: batch-quad base (rows bq + 16*mb)
  const int cq  = (tid >> 4) & 3;  // lane: unit within slice (col = g*4 + cq)
  const int ub  = tid >> 2;        // update batch
  const int uu  = tid & 3;         // update unit within slice
  const int gu  = sl * 4 + uu;

  if (tid < 16) bl[tid] = bsrc[(tid >> 2) * HID + sl * 4 + (tid & 3)];
  if (tid < 64) {
    int l = len[tid];
    #pragma unroll
    for (int off = 32; off; off >>= 1) l = max(l, __shfl_xor(l, off));
    if (tid == 0) s_maxlen = l;
  }
  const int len_ub = len[ub];

  // ---- one-time weight preload into LDS (reused for all 1000 timesteps) ----
  if (packed) {
    const float* wsrc = Wp + (size_t)(L * SLICES + sl) * (16 * KTOT);
    for (int i = tid * 4; i < 16 * KTOT; i += NTHR * 4) {
      const int col = i >> 10, k = i & (KTOT - 1);
      *(float4*)&Wl2[col * WP + k] = *(const float4*)(wsrc + i);
    }
  } else {
    for (int i = tid; i < 16 * KTOT; i += NTHR) {
      const int col = i >> 10, k = i & (KTOT - 1);
      Wl2[col * WP + k] =
          Wsrc[(size_t)k * 2048 + (col >> 2) * HID + sl * 4 + (col & 3)];
    }
  }
  __syncthreads();
  const int maxlen = s_maxlen;

  float c_st = 0.f, h_st = 0.f;
  unsigned target = 0;

  for (int r = 0; r <= maxlen; ++r) {
    const bool active = (L == 0) ? (r < maxlen) : (r >= 1);
    if (active) {
      const int t = (L == 0) ? r : (r - 1);

      const float* hprev = (L ? h1b : h0b) + ((r + 1) & 1) * NB * HID + b * HID;
      const float* xsrc  = (L == 0)
          ? (emb + (size_t)tok[b * SEQT + t] * HID)
          : (y0b + ((r + 1) & 1) * NB * HID + b * HID);

      float acc[4][4] = {};  // [mb][gate] partials over this wave's k-window
      // lane tile: batches {bq+16*mb} x 4 gates of unit cq.
      // iv: 16 distinct 16B rows (2-way banks = free), 4-way broadcast over cq.
      // w : 4 distinct cols (conflict-free via WP), 16-way broadcast over bq.
      auto comp = [&](int c) {
        const float (*ivb)[64][4] = inl2[c & 1][seg];
        const int k0 = c * KCH + seg * 32;
        const float* w0 = &Wl2[(0 * 4 + cq) * WP + k0];
        const float* w1 = &Wl2[(1 * 4 + cq) * WP + k0];
        const float* w2 = &Wl2[(2 * 4 + cq) * WP + k0];
        const float* w3 = &Wl2[(3 * 4 + cq) * WP + k0];
        #pragma unroll
        for (int jj = 0; jj < 8; ++jj) {
          const f32x4 x0 = *(const f32x4*)ivb[jj][bq +  0];
          const f32x4 x1 = *(const f32x4*)ivb[jj][bq + 16];
          const f32x4 x2 = *(const f32x4*)ivb[jj][bq + 32];
          const f32x4 x3 = *(const f32x4*)ivb[jj][bq + 48];
          const f32x4 g0 = *(const f32x4*)(w0 + jj * 4);
          const f32x4 g1 = *(const f32x4*)(w1 + jj * 4);
          const f32x4 g2 = *(const f32x4*)(w2 + jj * 4);
          const f32x4 g3 = *(const f32x4*)(w3 + jj * 4);
          #pragma unroll
          for (int e = 0; e < 4; ++e) {
            acc[0][0] = fmaf(x0[e], g0[e], acc[0][0]);
            acc[0][1] = fmaf(x0[e], g1[e], acc[0][1]);
            acc[0][2] = fmaf(x0[e], g2[e], acc[0][2]);
            acc[0][3] = fmaf(x0[e], g3[e], acc[0][3]);
            acc[1][0] = fmaf(x1[e], g0[e], acc[1][0]);
            acc[1][1] = fmaf(x1[e], g1[e], acc[1][1]);
            acc[1][2] = fmaf(x1[e], g2[e], acc[1][2]);
            acc[1][3] = fmaf(x1[e], g3[e], acc[1][3]);
            acc[2][0] = fmaf(x2[e], g0[e], acc[2][0]);
            acc[2][1] = fmaf(x2[e], g1[e], acc[2][1]);
            acc[2][2] = fmaf(x2[e], g2[e], acc[2][2]);
            acc[2][3] = fmaf(x2[e], g3[e], acc[2][3]);
            acc[3][0] = fmaf(x3[e], g0[e], acc[3][0]);
            acc[3][1] = fmaf(x3[e], g1[e], acc[3][1]);
            acc[3][2] = fmaf(x3[e], g2[e], acc[3][2]);
            acc[3][3] = fmaf(x3[e], g3[e], acc[3][3]);
          }
        }
      };

      // ---- BISECT: serial per-chunk stage->comp, compiler-managed waits ----
      // No asm, no counted vmcnt, no DMA, no manual pipeline. Staging is
      // UNCONDITIONAL (dead-batch values provably discarded downstream).
      // inl2 is wave-private via [seg] -> no barriers needed; same-wave DS
      // ordering makes the [c&1] buffer reuse safe.
      for (int c = 0; c < 8; ++c) {
        const float* src =
            ((c < 4) ? (xsrc + c * KCH) : (hprev + (c - 4) * KCH)) + seg * 32;
        ull v[16];
        if (c < 4 && L == 0) {              // emb: normal cached loads
          #pragma unroll
          for (int i = 0; i < 16; ++i) v[i] = *(const ull*)(src + 2 * i);
        } else {                            // exchange buffers: LLC-coherent
          #pragma unroll
          for (int i = 0; i < 16; ++i) v[i] = ld_llc8(src + 2 * i);
        }
        float (*dstb)[64][4] = inl2[c & 1][seg];   // [jj][row][e]
        #pragma unroll
        for (int jj = 0; jj < 8; ++jj) {
          *(ull*)&dstb[jj][b][0] = v[2 * jj];
          *(ull*)&dstb[jj][b][2] = v[2 * jj + 1];
        }
        comp(c);
      }

      // ---- K-reduction: 4 wave-partials per (b, unit, gate) via glp ----
      #pragma unroll
      for (int mb = 0; mb < 4; ++mb)
        #pragma unroll
        for (int g = 0; g < 4; ++g)
          glp[(bq + 16 * mb) * GP + cq * 16 + g * 4 + seg] = acc[mb][g];
      __syncthreads();

      // ---- cell update: thread (ub, uu) sums its 4 segs per gate ----
      const float* gp = &glp[ub * GP + uu * 16];
      const f32x4 q0 = *(const f32x4*)(gp + 0);
      const f32x4 q1 = *(const f32x4*)(gp + 4);
      const f32x4 q2 = *(const f32x4*)(gp + 8);
      const f32x4 q3 = *(const f32x4*)(gp + 12);
      const bool alive = (t < len_ub);
      float gi = (q0[0] + q0[1]) + (q0[2] + q0[3]) + bl[uu];
      float gj = (q1[0] + q1[1]) + (q1[2] + q1[3]) + bl[4 + uu];
      float gf = (q2[0] + q2[1]) + (q2[2] + q2[3]) + bl[8 + uu];
      float go = (q3[0] + q3[1]) + (q3[2] + q3[3]) + bl[12 + uu];
      float cn = sigm(gf) * c_st + sigm(gi) * tanh_f(gj);
      float hn = sigm(go) * tanh_f(cn);
      if (alive) { c_st = cn; h_st = hn; }
      float* hb = (L ? h1b : h0b) + (r & 1) * NB * HID;
      st_llc(&hb[ub * HID + gu], h_st);
      if (L == 0) {
        st_llc(&y0b[(r & 1) * NB * HID + ub * HID + gu], alive ? hn : 0.f);
      } else if (t == len_ub - 1) {
        st_llc(&lastb[ub * HID + gu], hn);
      }
    }

    // ---- fence-free grid barrier: WT stores already at LLC; readers bypass L2 ----
    target += NWG;
    asm volatile("s_waitcnt vmcnt(0) lgkmcnt(0)" ::: "memory");
    __syncthreads();
    if (tid == 0) {
      __hip_atomic_fetch_add(cnt, 1u, __ATOMIC_RELAXED, __HIP_MEMORY_SCOPE_AGENT);
      while (__hip_atomic_load(cnt, __ATOMIC_RELAXED, __HIP_MEMORY_SCOPE_AGENT) < target)
        __builtin_amdgcn_s_sleep(1);
    }
    __syncthreads();
  }

  // ---- epilogue: logits = last @ Wout + bout ----
  const int go_ = wg * NTHR + tid;
  if (go_ < NB * NENT) {
    const int bb = go_ / NENT;
    const int e  = go_ - bb * NENT;
    const float* lrow = lastb + bb * HID;
    float s = bout[e];
    #pragma unroll 8
    for (int k = 0; k < HID; ++k)
      s = fmaf(ld_llc4(lrow + k), Wout[k * NENT + e], s);
    out[go_] = s;
  }
}

extern "C" void kernel_launch(void* const* d_in, const int* in_sizes, int n_in,
                              void* d_out, int out_size, void* d_ws, size_t ws_size,
                              hipStream_t stream) {
  (void)in_sizes; (void)n_in; (void)out_size;
  const int*   tok  = (const int*)d_in[0];
  const int*   len  = (const int*)d_in[1];
  const float* emb  = (const float*)d_in[2];
  const float* W0   = (const float*)d_in[3];
  const float* b0   = (const float*)d_in[4];
  const float* W1   = (const float*)d_in[5];
  const float* b1   = (const float*)d_in[6];
  const float* Wout = (const float*)d_in[7];
  const float* bout = (const float*)d_in[8];
  float* out = (float*)d_out;
  unsigned char* ws = (unsigned char*)d_ws;

  // ws layout: [0,256) counter | exchange (7*128 KB) | packed W (16 MB, 256-aligned)
  const size_t zbytes   = 256 + (size_t)7 * NB * HID * sizeof(float);
  const size_t pack_off = (zbytes + 255) & ~(size_t)255;
  const size_t pack_sz  = (size_t)2 * SLICES * 16 * KTOT * sizeof(float); // 16 MB
  const int    packed   = (ws_size >= pack_off + pack_sz) ? 1 : 0;
  float* Wp = (float*)(ws + pack_off);

  hipMemsetAsync(ws, 0, zbytes, stream);
  if (packed) {
    const int n = 2 * SLICES * 16 * KTOT;             // 4,194,304 floats
    pack_w<<<n / 256, 256, 0, stream>>>(W0, W1, Wp);
  }

  void* args[] = {(void*)&tok, (void*)&len, (void*)&emb, (void*)&W0, (void*)&b0,
                  (void*)&W1, (void*)&b1, (void*)&Wout, (void*)&bout,
                  (void*)&out, (void*)&ws, (void*)&Wp, (void*)&packed};
  hipLaunchCooperativeKernel((const void*)lstm_persistent, dim3(NWG), dim3(NTHR),
                             args, 0, stream);
}